// Round 8
// baseline (515.402 us; speedup 1.0000x reference)
//
#include <hip/hip_runtime.h>

typedef unsigned short u16;
typedef short bf8v __attribute__((ext_vector_type(8)));
typedef float f4v __attribute__((ext_vector_type(4)));
typedef float f16v __attribute__((ext_vector_type(16)));

#define DEV static __device__ __forceinline__

constexpr int BB   = 64;
constexpr int NV   = 21;
constexpr int BN   = BB * NV;       // 1344
constexpr int PNUM = 255;
constexpr int D    = 128;
constexpr int PRED = 96;
constexpr int ROWS = BN * PNUM;     // 342720 = 64 * 5355
constexpr int KH   = D * PNUM;      // 32640 head K
constexpr int CH   = 30;            // head K chunks
constexpr int KPC  = KH / CH;       // 1088 = 34*32
constexpr int HITER = KPC / 32;     // 34
constexpr int LSTR = 132;           // LDS row stride (u16); rows 8B-aligned, 2-way banks (free)
constexpr float EMA_SCALE = 0.70710678118654752440f;  // 1/sqrt(2)

DEV float bf2f(u16 h) { return __uint_as_float(((unsigned)h) << 16); }
DEV u16 f2bf(float f) {  // RNE (weight prepass only)
  unsigned u = __float_as_uint(f);
  return (u16)((u + 0x7fffu + ((u >> 16) & 1u)) >> 16);
}
// pack two floats to bf16 pair (round-half-up): lo = a, hi = b
DEV unsigned pkbf2(float a, float b) {
  unsigned ua = __float_as_uint(a) + 0x8000u;
  unsigned ub = __float_as_uint(b) + 0x8000u;
  return __builtin_amdgcn_perm(ub, ua, 0x07060302u);
}
DEV bf8v mk4(unsigned a, unsigned b, unsigned c, unsigned d) {
  int4 t = {(int)a, (int)b, (int)c, (int)d};
  bf8v r;
  __builtin_memcpy(&r, &t, 16);
  return r;
}
DEV bf8v ld8(const u16* p) {  // alignment-safe 16B load (works for LDS at 8B align)
  bf8v r;
  __builtin_memcpy(&r, p, 16);
  return r;
}
DEV f4v mfma16(bf8v a, bf8v b, f4v c) {
  return __builtin_amdgcn_mfma_f32_16x16x32_bf16(a, b, c, 0, 0, 0);
}
DEV f16v mfma32(bf8v a, bf8v b, f16v c) {
  return __builtin_amdgcn_mfma_f32_32x32x16_bf16(a, b, c, 0, 0, 0);
}
DEV f16v zero16() {
  f16v r;
#pragma unroll
  for (int i = 0; i < 16; i++) r[i] = 0.f;
  return r;
}

// Sigma (bits 2<->3 of output channel) is baked into the staged weights, so a
// lane's D-registers hold canonical channels 32g+16(wq>>1)+4(wq&1)+8hh+i and a
// B-fragment for k-group ks is a pure register re-pack (no cross-lane op):
#define FRG(pk, ks)                                                            \
  mk4(pk[(ks) >> 1][2 * ((ks) & 1)][0], pk[(ks) >> 1][2 * ((ks) & 1)][1],      \
      pk[(ks) >> 1][2 * ((ks) & 1) + 1][0], pk[(ks) >> 1][2 * ((ks) & 1) + 1][1])

// ---------------- fused weight swizzle prepass (fp32 -> bf16 fragments) ----------------
// frag[((k>>3)*N + n)*8 + (k&7)] = src[k*N + perm(n)]; k >= K zero-filled.
// perm = swap bits 2,3 of n (involution; output-channel sigma).
__global__ void swz_all(
    const float* __restrict__ fw1, const float* __restrict__ fw2,
    const float* __restrict__ fwr, const float* __restrict__ ew1,
    const float* __restrict__ ew2, const float* __restrict__ ewr,
    const float* __restrict__ hw, u16* __restrict__ wb, u16* __restrict__ wsh) {
  int b = blockIdx.x;
  if (b >= 560) {  // head_w [d*255+l][96] -> fragments in k-order kp = l*128 + d (no perm)
    int i = (b - 560) * 256 + threadIdx.x;
    if (i >= KH * PRED) return;
    int kp = i / PRED, n = i - kp * PRED;
    int l = kp >> 7, d = kp & 127;
    wsh[((size_t)(kp >> 3) * PRED + n) * 8 + (kp & 7)] =
        f2bf(hw[(size_t)(d * PNUM + l) * PRED + n]);
    return;
  }
  const float* src; u16* dst; int K, N, Kp;
  if (b < 32)       { src = fw1; dst = wb;          K = 16;  N = 256; Kp = 32; }
  else if (b < 160) { b -= 32;  src = fw2; dst = wb + 8192;  K = 256; N = 128; Kp = 256; }
  else if (b < 176) { b -= 160; src = fwr; dst = wb + 40960; K = 16;  N = 128; Kp = 32; }
  else {
    int e = (b - 176) >> 6; b = (b - 176) & 63;
    int l = e / 3, w = e - 3 * l;
    const float* basep = (w == 0) ? ew1 : (w == 1) ? ew2 : ewr;
    src = basep + (size_t)l * 16384;
    dst = wb + 45056 + e * 16384;
    K = 128; N = 128; Kp = 128;
  }
  int i = b * 256 + threadIdx.x;
  if (i >= Kp * N) return;
  int k = i / N, n = i - k * N;
  int np = (n & ~12) | ((n & 4) << 1) | ((n & 8) >> 1);  // swap bits 2,3
  u16 v = (k < K) ? f2bf(src[(size_t)k * N + np]) : (u16)0;
  dst[((size_t)(k >> 3) * N + n) * 8 + (k & 7)] = v;
}

// ---------------- K1: fused gather + fp LEMblock + 2 encoder LEMblocks ----------------
// 32x32x16 MFMA, transposed (A=weight, B=act). Wave owns 32 rows (lane&31).
// GEMM1->GEMM2 fused group-wise (h never fully materialized: saves 64 VGPRs);
// encoder h2 staged through per-wave LDS rows (saves 32 VGPRs). Target 3 waves/SIMD.
__global__ __launch_bounds__(128, 3) void k_lem(
    const float* __restrict__ x,
    const u16* __restrict__ ws1, const float* __restrict__ b1,
    const u16* __restrict__ ws2, const u16* __restrict__ wsr,
    const float* __restrict__ b2, const float* __restrict__ br,
    const float* __restrict__ g, const float* __restrict__ be,
    const u16* __restrict__ wse, const float* __restrict__ eb1,
    const float* __restrict__ eb2, const float* __restrict__ ebr,
    const float* __restrict__ eg, const float* __restrict__ ebe,
    u16* __restrict__ zout) {
  __shared__ __align__(16) u16 zst[64 * LSTR];
  const int t = threadIdx.x;
  const int lane = t & 63, w = t >> 6;  // w: wave 0..1
  const int hh = lane >> 5, r5 = lane & 31;
  const int tile = blockIdx.x;
  const int row = tile * 64 + w * 32 + r5;
  u16* zrow = zst + (w * 32 + r5) * LSTR;

  // gather z0: lane holds patch elems [8*hh .. 8*hh+7] of its row (B-frag K=16)
  bf8v azv;
  {
    unsigned R = (unsigned)row;
    unsigned bn = R / 255u;
    unsigned p = R - bn * 255u;
    const float* px = x + (size_t)bn * 2048u + p * 8u + hh * 8;
    float4 v0 = *(const float4*)px;
    float4 v1 = *(const float4*)(px + 4);
    azv = mk4(pkbf2(v0.x, v0.y), pkbf2(v0.z, v0.w),
              pkbf2(v1.x, v1.y), pkbf2(v1.z, v1.w));
  }

  f16v acc[4];
  unsigned zpk[4][4][2];  // packed z (128 chans, sigma slots)

  // ---- acc init: Wr^T z0 ----
  {
    bf8v wr4[4];
#pragma unroll
    for (int gg = 0; gg < 4; gg++)
      wr4[gg] = ld8(wsr + ((size_t)(hh * 128 + gg * 32 + r5)) * 8);
#pragma unroll
    for (int gg = 0; gg < 4; gg++) acc[gg] = mfma32(wr4[gg], azv, zero16());
  }

  // ---- fused GEMM1+GEMM2: per h-group gg (32 chans), produce & consume ----
  {
    bf8v w2b[2][8];  // [buf][gg2*2+kk]
    bf8v w1c = ld8(ws1 + ((size_t)(hh * 256 + r5)) * 8);
#pragma unroll
    for (int q = 0; q < 8; q++) {
      int gg2 = q >> 1, kk = q & 1;
      w2b[0][q] = ld8(ws2 + ((size_t)((2 * kk + hh) * 128 + gg2 * 32 + r5)) * 8);
    }
#pragma unroll
    for (int gg = 0; gg < 8; gg++) {
      int cur = gg & 1;
      f16v a = mfma32(w1c, azv, zero16());
      if (gg < 7) {
        w1c = ld8(ws1 + ((size_t)(hh * 256 + (gg + 1) * 32 + r5)) * 8);
#pragma unroll
        for (int q = 0; q < 8; q++) {
          int gg2 = q >> 1, kk = q & 1;
          w2b[cur ^ 1][q] =
              ld8(ws2 + ((size_t)((4 * (gg + 1) + 2 * kk + hh) * 128 + gg2 * 32 + r5)) * 8);
        }
      }
      unsigned pk[4][2];
#pragma unroll
      for (int wq = 0; wq < 4; wq++) {
        int c0 = gg * 32 + ((wq >> 1) << 4) + ((wq & 1) << 2) + (hh << 3);
        float4 bv = *(const float4*)(b1 + c0);
        float v0 = fmaxf(a[wq * 4 + 0] + bv.x, 0.f);
        float v1 = fmaxf(a[wq * 4 + 1] + bv.y, 0.f);
        float v2 = fmaxf(a[wq * 4 + 2] + bv.z, 0.f);
        float v3 = fmaxf(a[wq * 4 + 3] + bv.w, 0.f);
        pk[wq][0] = pkbf2(v0, v1);
        pk[wq][1] = pkbf2(v2, v3);
      }
      bf8v fr0 = mk4(pk[0][0], pk[0][1], pk[1][0], pk[1][1]);
      bf8v fr1 = mk4(pk[2][0], pk[2][1], pk[3][0], pk[3][1]);
#pragma unroll
      for (int gg2 = 0; gg2 < 4; gg2++) {
        acc[gg2] = mfma32(w2b[cur][gg2 * 2 + 0], fr0, acc[gg2]);
        acc[gg2] = mfma32(w2b[cur][gg2 * 2 + 1], fr1, acc[gg2]);
      }
    }
  }
  // ---- bias + LN -> zpk ----
  {
    float s = 0.f, s2 = 0.f;
#pragma unroll
    for (int gg = 0; gg < 4; gg++)
#pragma unroll
      for (int wq = 0; wq < 4; wq++) {
        int c0 = gg * 32 + ((wq >> 1) << 4) + ((wq & 1) << 2) + (hh << 3);
        float4 bv2 = *(const float4*)(b2 + c0);
        float4 bvr = *(const float4*)(br + c0);
        acc[gg][wq * 4 + 0] += bv2.x + bvr.x;
        acc[gg][wq * 4 + 1] += bv2.y + bvr.y;
        acc[gg][wq * 4 + 2] += bv2.z + bvr.z;
        acc[gg][wq * 4 + 3] += bv2.w + bvr.w;
#pragma unroll
        for (int i = 0; i < 4; i++) { float v = acc[gg][wq * 4 + i]; s += v; s2 += v * v; }
      }
    s += __shfl_xor(s, 32, 64); s2 += __shfl_xor(s2, 32, 64);
    float mean = s * (1.f / 128.f);
    float rstd = rsqrtf(s2 * (1.f / 128.f) - mean * mean + 1e-5f);
#pragma unroll
    for (int gg = 0; gg < 4; gg++)
#pragma unroll
      for (int wq = 0; wq < 4; wq++) {
        int c0 = gg * 32 + ((wq >> 1) << 4) + ((wq & 1) << 2) + (hh << 3);
        float4 gv = *(const float4*)(g + c0);
        float4 bv = *(const float4*)(be + c0);
        float v0 = (acc[gg][wq * 4 + 0] - mean) * rstd * gv.x + bv.x;
        float v1 = (acc[gg][wq * 4 + 1] - mean) * rstd * gv.y + bv.y;
        float v2 = (acc[gg][wq * 4 + 2] - mean) * rstd * gv.z + bv.z;
        float v3 = (acc[gg][wq * 4 + 3] - mean) * rstd * gv.w + bv.w;
        zpk[gg][wq][0] = pkbf2(v0, v1);
        zpk[gg][wq][1] = pkbf2(v2, v3);
      }
  }

  // ---- encoder layers ----
#pragma unroll 1
  for (int L = 0; L < 2; L++) {
    const u16* w1p = wse + (size_t)(L * 3 + 0) * 16384;
    const u16* w2p = wse + (size_t)(L * 3 + 1) * 16384;
    const u16* wrp = wse + (size_t)(L * 3 + 2) * 16384;
    // GEMM-A: a2 = W1^T z (K=128, 8 groups, dbuf weights); epilogue -> h2 in LDS
    {
      f16v a2[4];
#pragma unroll
      for (int gg = 0; gg < 4; gg++) a2[gg] = zero16();
      bf8v wqb[2][4];
#pragma unroll
      for (int gg = 0; gg < 4; gg++)
        wqb[0][gg] = ld8(w1p + ((size_t)(hh * 128 + gg * 32 + r5)) * 8);
#pragma unroll
      for (int u = 0; u < 8; u++) {
        int cur = u & 1;
        if (u < 7) {
#pragma unroll
          for (int gg = 0; gg < 4; gg++)
            wqb[cur ^ 1][gg] =
                ld8(w1p + ((size_t)((2 * (u + 1) + hh) * 128 + gg * 32 + r5)) * 8);
        }
        bf8v bfr = FRG(zpk, u);
#pragma unroll
        for (int gg = 0; gg < 4; gg++) a2[gg] = mfma32(wqb[cur][gg], bfr, a2[gg]);
      }
#pragma unroll
      for (int gg = 0; gg < 4; gg++) {
        unsigned pk[4][2];
#pragma unroll
        for (int wq = 0; wq < 4; wq++) {
          int c0 = gg * 32 + ((wq >> 1) << 4) + ((wq & 1) << 2) + (hh << 3);
          float4 bv = *(const float4*)(eb1 + L * 128 + c0);
          float v0 = fmaxf(a2[gg][wq * 4 + 0] + bv.x, 0.f);
          float v1 = fmaxf(a2[gg][wq * 4 + 1] + bv.y, 0.f);
          float v2 = fmaxf(a2[gg][wq * 4 + 2] + bv.z, 0.f);
          float v3 = fmaxf(a2[gg][wq * 4 + 3] + bv.w, 0.f);
          pk[wq][0] = pkbf2(v0, v1);
          pk[wq][1] = pkbf2(v2, v3);
        }
        // canonical row-major h2: chans [32gg+16p+8hh .. +7] at zrow+offset (8B aligned)
        uint2 p0 = {pk[0][0], pk[0][1]};
        uint2 p1 = {pk[1][0], pk[1][1]};
        uint2 p2 = {pk[2][0], pk[2][1]};
        uint2 p3 = {pk[3][0], pk[3][1]};
        *(uint2*)(zrow + gg * 32 + (hh << 3) + 0) = p0;
        *(uint2*)(zrow + gg * 32 + (hh << 3) + 4) = p1;
        *(uint2*)(zrow + gg * 32 + 16 + (hh << 3) + 0) = p2;
        *(uint2*)(zrow + gg * 32 + 16 + (hh << 3) + 4) = p3;
      }
    }
    // GEMM-B: acc = W2^T h2(LDS) + Wr^T z(regs), 16 virtual k-groups
#pragma unroll
    for (int gg = 0; gg < 4; gg++) acc[gg] = zero16();
    {
      bf8v wqb[2][4];
      bf8v hf[2];
#pragma unroll
      for (int gg = 0; gg < 4; gg++)
        wqb[0][gg] = ld8(w2p + ((size_t)(hh * 128 + gg * 32 + r5)) * 8);
      hf[0] = ld8(zrow + (hh << 3));  // frag u=0
#pragma unroll
      for (int u = 0; u < 16; u++) {
        int cur = u & 1;
        if (u + 1 < 16) {
          int v = u + 1;
          const u16* wp = (v < 8) ? w2p : wrp;
          int kg = v & 7;
#pragma unroll
          for (int gg = 0; gg < 4; gg++)
            wqb[cur ^ 1][gg] = ld8(wp + ((size_t)((2 * kg + hh) * 128 + gg * 32 + r5)) * 8);
          if (v < 8) hf[cur ^ 1] = ld8(zrow + v * 16 + (hh << 3));
        }
        bf8v bfr = (u < 8) ? hf[cur] : FRG(zpk, (u - 8));
#pragma unroll
        for (int gg = 0; gg < 4; gg++) acc[gg] = mfma32(wqb[cur][gg], bfr, acc[gg]);
      }
    }
    // bias + LN
    float s = 0.f, s2 = 0.f;
#pragma unroll
    for (int gg = 0; gg < 4; gg++)
#pragma unroll
      for (int wq = 0; wq < 4; wq++) {
        int c0 = gg * 32 + ((wq >> 1) << 4) + ((wq & 1) << 2) + (hh << 3);
        float4 bv2 = *(const float4*)(eb2 + L * 128 + c0);
        float4 bvr = *(const float4*)(ebr + L * 128 + c0);
        acc[gg][wq * 4 + 0] += bv2.x + bvr.x;
        acc[gg][wq * 4 + 1] += bv2.y + bvr.y;
        acc[gg][wq * 4 + 2] += bv2.z + bvr.z;
        acc[gg][wq * 4 + 3] += bv2.w + bvr.w;
#pragma unroll
        for (int i = 0; i < 4; i++) { float v = acc[gg][wq * 4 + i]; s += v; s2 += v * v; }
      }
    s += __shfl_xor(s, 32, 64); s2 += __shfl_xor(s2, 32, 64);
    float mean = s * (1.f / 128.f);
    float rstd = rsqrtf(s2 * (1.f / 128.f) - mean * mean + 1e-5f);
#pragma unroll
    for (int gg = 0; gg < 4; gg++)
#pragma unroll
      for (int wq = 0; wq < 4; wq++) {
        int c0 = gg * 32 + ((wq >> 1) << 4) + ((wq & 1) << 2) + (hh << 3);
        float4 gv = *(const float4*)(eg + L * 128 + c0);
        float4 bv = *(const float4*)(ebe + L * 128 + c0);
        float v0 = (acc[gg][wq * 4 + 0] - mean) * rstd * gv.x + bv.x;
        float v1 = (acc[gg][wq * 4 + 1] - mean) * rstd * gv.y + bv.y;
        float v2 = (acc[gg][wq * 4 + 2] - mean) * rstd * gv.z + bv.z;
        float v3 = (acc[gg][wq * 4 + 3] - mean) * rstd * gv.w + bv.w;
        unsigned plo = pkbf2(v0, v1), phi = pkbf2(v2, v3);
        if (L == 0) {
          zpk[gg][wq][0] = plo;
          zpk[gg][wq][1] = phi;
        } else {
          uint2 pv = {plo, phi};
          *(uint2*)(zrow + c0) = pv;  // de-permuted by address
        }
      }
  }

  // per-wave coalesced store of its own 32 rows (same-wave LDS RAW: no barrier)
#pragma unroll
  for (int it = 0; it < 8; it++) {
    int lu = it * 64 + lane;
    int rr = lu >> 4, seg = lu & 15;
    int orow = w * 32 + rr;
    *(uint4*)(zout + ((size_t)tile * 64 + orow) * 128 + seg * 8) =
        *(const uint4*)(zst + orow * LSTR + seg * 8);
  }
}

// ---------------- K2: MultiHeadEMA (2-state scan) + residual + silu, IN-PLACE ----------------
__global__ __launch_bounds__(128) void k_ema(
    u16* __restrict__ z,
    const float* __restrict__ pdel, const float* __restrict__ palp,
    const float* __restrict__ pbet, const float* __restrict__ pgam,
    const float* __restrict__ pome) {
  __shared__ __align__(16) u16 zc[64 * 128];
  const int t = threadIdx.x;  // channel d
  const int bn = blockIdx.x;
  float p0 = 1.f / (1.f + __expf(-pdel[t * 2 + 0]));
  float p1 = 1.f / (1.f + __expf(-pdel[t * 2 + 1]));
  float q0 = 1.f - p0 / (1.f + __expf(-palp[t * 2 + 0]));
  float q1 = 1.f - p1 / (1.f + __expf(-palp[t * 2 + 1]));
  float w0 = p0 * pbet[t * 2 + 0] * pgam[t * 2 + 0] * EMA_SCALE;
  float w1 = p1 * pbet[t * 2 + 1] * pgam[t * 2 + 1] * EMA_SCALE;
  float om = pome[t];
  float s0 = 0.f, s1 = 0.f;
  u16* slab = z + (size_t)bn * KH;

  for (int ch = 0; ch < 4; ch++) {
    int nrow = (ch < 3) ? 64 : 63;
    int nval = nrow * 128;
    for (int i = t * 8; i < nval; i += 128 * 8)
      *(uint4*)(zc + i) = *(const uint4*)(slab + ch * 8192 + i);
    __syncthreads();
    for (int j0 = 0; j0 < nrow; j0 += 8) {
      float xs[8];
#pragma unroll
      for (int jj = 0; jj < 8; jj++)
        if (j0 + jj < nrow) xs[jj] = bf2f(zc[(j0 + jj) * 128 + t]);
#pragma unroll
      for (int jj = 0; jj < 8; jj++)
        if (j0 + jj < nrow) {
          float xv = xs[jj];
          s0 = q0 * s0 + xv;
          s1 = q1 * s1 + xv;
          float v = w0 * s0 + w1 * s1 + om * xv;
          xs[jj] = v / (1.f + __expf(-v));  // silu
        }
#pragma unroll
      for (int jj = 0; jj < 8; jj++)
        if (j0 + jj < nrow)
          zc[(j0 + jj) * 128 + t] = (u16)((__float_as_uint(xs[jj]) + 0x8000u) >> 16);
    }
    __syncthreads();
    for (int i = t * 8; i < nval; i += 128 * 8)
      *(uint4*)(slab + ch * 8192 + i) = *(const uint4*)(zc + i);
    __syncthreads();
  }
}

// ---------------- K3: head GEMM partials (K split into 30 chunks of 1088) ----------------
__global__ __launch_bounds__(256) void k_head(
    const u16* __restrict__ u, const u16* __restrict__ whs, float* __restrict__ part) {
  const int t = threadIdx.x;
  const int lane = t & 63, wid = t >> 6;
  const int quad = lane >> 4, lc = lane & 15;
  const int tile = blockIdx.x;  // 0..20
  const int ch = blockIdx.y;    // 0..29
  const int m0 = tile * 64 + wid * 16;
  const u16* Ab = u + (size_t)(m0 + lc) * KH + (size_t)ch * KPC;
  const int g0 = ch * (KPC / 8);  // base k-group
  f4v acc[6];
#pragma unroll
  for (int n = 0; n < 6; n++) acc[n] = (f4v){0.f, 0.f, 0.f, 0.f};
  bf8v a_nxt = ld8(Ab + quad * 8);
  bf8v b_nxt[6];
#pragma unroll
  for (int n = 0; n < 6; n++)
    b_nxt[n] = ld8(whs + ((size_t)(g0 + quad) * PRED + n * 16 + lc) * 8);
  for (int ks = 0; ks < HITER; ks++) {
    bf8v a_cur = a_nxt;
    bf8v b_cur[6];
#pragma unroll
    for (int n = 0; n < 6; n++) b_cur[n] = b_nxt[n];
    if (ks < HITER - 1) {
      a_nxt = ld8(Ab + (ks + 1) * 32 + quad * 8);
#pragma unroll
      for (int n = 0; n < 6; n++)
        b_nxt[n] = ld8(whs + ((size_t)(g0 + (ks + 1) * 4 + quad) * PRED + n * 16 + lc) * 8);
    }
#pragma unroll
    for (int n = 0; n < 6; n++) acc[n] = mfma16(a_cur, b_cur[n], acc[n]);
  }
#pragma unroll
  for (int n = 0; n < 6; n++) {
    int col = n * 16 + lc;
#pragma unroll
    for (int r = 0; r < 4; r++)
      part[((size_t)ch * BN + m0 + quad * 4 + r) * PRED + col] = acc[n][r];
  }
}

// ---------------- K4: reduce partials + bias -> fp32 out ----------------
__global__ __launch_bounds__(256) void k_red(
    const float* __restrict__ part, const float* __restrict__ hb, float* __restrict__ out) {
  int i = blockIdx.x * 256 + threadIdx.x;
  if (i >= BN * PRED) return;
  int row = i / PRED, col = i - row * PRED;
  float s = hb[col];
#pragma unroll 5
  for (int c = 0; c < CH; c++) s += part[((size_t)c * BN + row) * PRED + col];
  out[i] = s;
}

// ---------------- host ----------------
extern "C" void kernel_launch(void* const* d_in, const int* in_sizes, int n_in,
                              void* d_out, int out_size, void* d_ws, size_t ws_size,
                              hipStream_t stream) {
  const float* x      = (const float*)d_in[0];
  const float* fp_w1  = (const float*)d_in[1];
  const float* fp_b1  = (const float*)d_in[2];
  const float* fp_w2  = (const float*)d_in[3];
  const float* fp_b2  = (const float*)d_in[4];
  const float* fp_wr  = (const float*)d_in[5];
  const float* fp_br  = (const float*)d_in[6];
  const float* fp_g   = (const float*)d_in[7];
  const float* fp_be  = (const float*)d_in[8];
  const float* enc_w1 = (const float*)d_in[9];
  const float* enc_b1 = (const float*)d_in[10];
  const float* enc_w2 = (const float*)d_in[11];
  const float* enc_b2 = (const float*)d_in[12];
  const float* enc_wr = (const float*)d_in[13];
  const float* enc_br = (const float*)d_in[14];
  const float* enc_g  = (const float*)d_in[15];
  const float* enc_be = (const float*)d_in[16];
  const float* e_del  = (const float*)d_in[17];
  const float* e_alp  = (const float*)d_in[18];
  const float* e_bet  = (const float*)d_in[19];
  const float* e_gam  = (const float*)d_in[20];
  const float* e_om   = (const float*)d_in[21];
  const float* head_w = (const float*)d_in[22];
  const float* head_b = (const float*)d_in[23];

  // ws layout (bytes):
  //   [0, 87736320)             z3 / u  (bf16, [ROWS][128])
  //   [87736320, 103219200)     part    (fp32, [30][1344][96])
  //   [103219200, ...)          swizzled bf16 weights (~6.6 MB)
  char* base = (char*)d_ws;
  u16* z3 = (u16*)base;
  const size_t EZB = (size_t)ROWS * 128 * 2;        // 87,736,320
  float* part = (float*)(base + EZB);
  const size_t PARTB = (size_t)CH * BN * PRED * 4;  // 15,482,880
  u16* wb = (u16*)(base + EZB + PARTB);
  // wb offsets (u16): ws1=0(8192), ws2=8192(32768), wsr=40960(4096),
  //                   wse=45056(6*16384), wsh=143360(32640*96)
  u16* ws1 = wb;
  u16* ws2 = wb + 8192;
  u16* wsr = wb + 40960;
  u16* wse = wb + 45056;
  u16* wsh = wb + 143360;

  swz_all<<<560 + (KH * PRED + 255) / 256, 256, 0, stream>>>(
      fp_w1, fp_w2, fp_wr, enc_w1, enc_w2, enc_wr, head_w, wb, wsh);

  k_lem<<<ROWS / 64, 128, 0, stream>>>(x, ws1, fp_b1, ws2, wsr, fp_b2, fp_br, fp_g, fp_be,
                                       wse, enc_b1, enc_b2, enc_br, enc_g, enc_be, z3);
  k_ema<<<BN, 128, 0, stream>>>(z3, e_del, e_alp, e_bet, e_gam, e_om);
  k_head<<<dim3(21, CH), 256, 0, stream>>>(z3, wsh, part);
  k_red<<<(BN * PRED + 255) / 256, 256, 0, stream>>>(part, head_b, (float*)d_out);
}

// Round 9
// 405.455 us; speedup vs baseline: 1.2712x; 1.2712x over previous
//
#include <hip/hip_runtime.h>

typedef unsigned short u16;
typedef short bf8v __attribute__((ext_vector_type(8)));
typedef float f4v __attribute__((ext_vector_type(4)));
typedef float f16v __attribute__((ext_vector_type(16)));

#define DEV static __device__ __forceinline__

constexpr int BB   = 64;
constexpr int NV   = 21;
constexpr int BN   = BB * NV;       // 1344
constexpr int PNUM = 255;
constexpr int D    = 128;
constexpr int PRED = 96;
constexpr int ROWS = BN * PNUM;     // 342720 = 64 * 5355
constexpr int KH   = D * PNUM;      // 32640 head K
constexpr int CH   = 30;            // head K chunks
constexpr int KPC  = KH / CH;       // 1088 = 34*32
constexpr int HITER = KPC / 32;     // 34
constexpr float EMA_SCALE = 0.70710678118654752440f;  // 1/sqrt(2)

DEV float bf2f(u16 h) { return __uint_as_float(((unsigned)h) << 16); }
DEV u16 f2bf(float f) {  // RNE (weight prepass only)
  unsigned u = __float_as_uint(f);
  return (u16)((u + 0x7fffu + ((u >> 16) & 1u)) >> 16);
}
// pack two floats to bf16 pair (round-half-up): lo = a, hi = b
DEV unsigned pkbf2(float a, float b) {
  unsigned ua = __float_as_uint(a) + 0x8000u;
  unsigned ub = __float_as_uint(b) + 0x8000u;
  return __builtin_amdgcn_perm(ub, ua, 0x07060302u);
}
DEV bf8v mk4(unsigned a, unsigned b, unsigned c, unsigned d) {
  int4 t = {(int)a, (int)b, (int)c, (int)d};
  bf8v r;
  __builtin_memcpy(&r, &t, 16);
  return r;
}
DEV bf8v ld8(const u16* p) {
  bf8v r;
  __builtin_memcpy(&r, p, 16);
  return r;
}
DEV f4v mfma16(bf8v a, bf8v b, f4v c) {
  return __builtin_amdgcn_mfma_f32_16x16x32_bf16(a, b, c, 0, 0, 0);
}
DEV f16v mfma32(bf8v a, bf8v b, f16v c) {
  return __builtin_amdgcn_mfma_f32_32x32x16_bf16(a, b, c, 0, 0, 0);
}
DEV f16v zero16() {
  f16v r;
#pragma unroll
  for (int i = 0; i < 16; i++) r[i] = 0.f;
  return r;
}

// Sigma (bits 2<->3 of output channel) is baked into the staged weights, so a
// lane's D-registers hold canonical channels 32g+16(wq>>1)+4(wq&1)+8hh+i and a
// B-fragment for k-group ks is a pure register re-pack (no cross-lane op):
#define FRG(pk, ks)                                                            \
  mk4(pk[(ks) >> 1][2 * ((ks) & 1)][0], pk[(ks) >> 1][2 * ((ks) & 1)][1],      \
      pk[(ks) >> 1][2 * ((ks) & 1) + 1][0], pk[(ks) >> 1][2 * ((ks) & 1) + 1][1])

// ---------------- fused weight swizzle prepass (fp32 -> bf16 fragments) ----------------
// frag[((k>>3)*N + n)*8 + (k&7)] = src[k*N + perm(n)]; k >= K zero-filled.
// perm = swap bits 2,3 of n (involution; output-channel sigma).
__global__ void swz_all(
    const float* __restrict__ fw1, const float* __restrict__ fw2,
    const float* __restrict__ fwr, const float* __restrict__ ew1,
    const float* __restrict__ ew2, const float* __restrict__ ewr,
    const float* __restrict__ hw, u16* __restrict__ wb, u16* __restrict__ wsh) {
  int b = blockIdx.x;
  if (b >= 560) {  // head_w [d*255+l][96] -> fragments in k-order kp = l*128 + d (no perm)
    int i = (b - 560) * 256 + threadIdx.x;
    if (i >= KH * PRED) return;
    int kp = i / PRED, n = i - kp * PRED;
    int l = kp >> 7, d = kp & 127;
    wsh[((size_t)(kp >> 3) * PRED + n) * 8 + (kp & 7)] =
        f2bf(hw[(size_t)(d * PNUM + l) * PRED + n]);
    return;
  }
  const float* src; u16* dst; int K, N, Kp;
  if (b < 32)       { src = fw1; dst = wb;          K = 16;  N = 256; Kp = 32; }
  else if (b < 160) { b -= 32;  src = fw2; dst = wb + 8192;  K = 256; N = 128; Kp = 256; }
  else if (b < 176) { b -= 160; src = fwr; dst = wb + 40960; K = 16;  N = 128; Kp = 32; }
  else {
    int e = (b - 176) >> 6; b = (b - 176) & 63;
    int l = e / 3, w = e - 3 * l;
    const float* basep = (w == 0) ? ew1 : (w == 1) ? ew2 : ewr;
    src = basep + (size_t)l * 16384;
    dst = wb + 45056 + e * 16384;
    K = 128; N = 128; Kp = 128;
  }
  int i = b * 256 + threadIdx.x;
  if (i >= Kp * N) return;
  int k = i / N, n = i - k * N;
  int np = (n & ~12) | ((n & 4) << 1) | ((n & 8) >> 1);  // swap bits 2,3
  u16 v = (k < K) ? f2bf(src[(size_t)k * N + np]) : (u16)0;
  dst[((size_t)(k >> 3) * N + n) * 8 + (k & 7)] = v;
}

// ---------------- K1: fused gather + fp LEMblock + 2 encoder LEMblocks ----------------
// 32x32x16 MFMA, transposed (A=weight, B=act). Wave owns 32 rows (lane&31).
// Sigma weights make inter-GEMM relayout free (register repack, no shuffles).
// Depth-1 double-buffered weight prefetch ONLY (R7/R8 showed deeper prefetch /
// occupancy caps spill to scratch: the 2-wave register budget is the floor).
__global__ __launch_bounds__(128, 2) void k_lem(
    const float* __restrict__ x,
    const u16* __restrict__ ws1, const float* __restrict__ b1,
    const u16* __restrict__ ws2, const u16* __restrict__ wsr,
    const float* __restrict__ b2, const float* __restrict__ br,
    const float* __restrict__ g, const float* __restrict__ be,
    const u16* __restrict__ wse, const float* __restrict__ eb1,
    const float* __restrict__ eb2, const float* __restrict__ ebr,
    const float* __restrict__ eg, const float* __restrict__ ebe,
    u16* __restrict__ zout) {
  __shared__ __align__(16) u16 zst[64 * 132];
  const int t = threadIdx.x;
  const int lane = t & 63, w = t >> 6;  // w: wave 0..1
  const int hh = lane >> 5, r5 = lane & 31;
  const int tile = blockIdx.x;
  const int row = tile * 64 + w * 32 + r5;

  // gather z0: lane holds patch elems [8*hh .. 8*hh+7] of its row (B-frag K=16)
  bf8v azv;
  {
    unsigned R = (unsigned)row;
    unsigned bn = R / 255u;
    unsigned p = R - bn * 255u;
    const float* px = x + (size_t)bn * 2048u + p * 8u + hh * 8;
    float4 v0 = *(const float4*)px;
    float4 v1 = *(const float4*)(px + 4);
    azv = mk4(pkbf2(v0.x, v0.y), pkbf2(v0.z, v0.w),
              pkbf2(v1.x, v1.y), pkbf2(v1.z, v1.w));
  }

  unsigned hpk[8][4][2];  // packed h (256 chans, sigma slots)
  unsigned zpk[4][4][2];  // packed z (128 chans, sigma slots)

  // ---- GEMM1: h = relu(W1^T z0 + b1), two halves of 128 cols ----
#pragma unroll
  for (int half = 0; half < 2; half++) {
    f16v a[4];
#pragma unroll
    for (int gg = 0; gg < 4; gg++) {
      bf8v wf = ld8(ws1 + ((size_t)(hh * 256 + (half * 4 + gg) * 32 + r5)) * 8);
      a[gg] = mfma32(wf, azv, zero16());
    }
#pragma unroll
    for (int gg = 0; gg < 4; gg++)
#pragma unroll
      for (int wq = 0; wq < 4; wq++) {
        int c0 = (half * 4 + gg) * 32 + ((wq >> 1) << 4) + ((wq & 1) << 2) + (hh << 3);
        float4 bv = *(const float4*)(b1 + c0);
        float v0 = fmaxf(a[gg][wq * 4 + 0] + bv.x, 0.f);
        float v1 = fmaxf(a[gg][wq * 4 + 1] + bv.y, 0.f);
        float v2 = fmaxf(a[gg][wq * 4 + 2] + bv.z, 0.f);
        float v3 = fmaxf(a[gg][wq * 4 + 3] + bv.w, 0.f);
        hpk[half * 4 + gg][wq][0] = pkbf2(v0, v1);
        hpk[half * 4 + gg][wq][1] = pkbf2(v2, v3);
      }
  }

  // ---- GEMM2: y1 = W2^T h + Wr^T z0 + b2 + br -> LN -> z1 ----
  f16v acc[4];
  {
    {
      bf8v wr4[4];
#pragma unroll
      for (int gg = 0; gg < 4; gg++)
        wr4[gg] = ld8(wsr + ((size_t)(hh * 128 + gg * 32 + r5)) * 8);
#pragma unroll
      for (int gg = 0; gg < 4; gg++) acc[gg] = mfma32(wr4[gg], azv, zero16());
    }
    bf8v wq[2][4];
#pragma unroll
    for (int gg = 0; gg < 4; gg++)
      wq[0][gg] = ld8(ws2 + ((size_t)(hh * 128 + gg * 32 + r5)) * 8);
#pragma unroll
    for (int u = 0; u < 16; u++) {
      int cur = u & 1;
      if (u + 1 < 16) {
#pragma unroll
        for (int gg = 0; gg < 4; gg++)
          wq[cur ^ 1][gg] =
              ld8(ws2 + ((size_t)((2 * (u + 1) + hh) * 128 + gg * 32 + r5)) * 8);
      }
      bf8v bfr = FRG(hpk, u);
#pragma unroll
      for (int gg = 0; gg < 4; gg++) acc[gg] = mfma32(wq[cur][gg], bfr, acc[gg]);
    }
    // bias + LN
    float s = 0.f, s2 = 0.f;
#pragma unroll
    for (int gg = 0; gg < 4; gg++)
#pragma unroll
      for (int wq4 = 0; wq4 < 4; wq4++) {
        int c0 = gg * 32 + ((wq4 >> 1) << 4) + ((wq4 & 1) << 2) + (hh << 3);
        float4 bv2 = *(const float4*)(b2 + c0);
        float4 bvr = *(const float4*)(br + c0);
        acc[gg][wq4 * 4 + 0] += bv2.x + bvr.x;
        acc[gg][wq4 * 4 + 1] += bv2.y + bvr.y;
        acc[gg][wq4 * 4 + 2] += bv2.z + bvr.z;
        acc[gg][wq4 * 4 + 3] += bv2.w + bvr.w;
#pragma unroll
        for (int sidx = 0; sidx < 4; sidx++) {
          float v = acc[gg][wq4 * 4 + sidx];
          s += v; s2 += v * v;
        }
      }
    s += __shfl_xor(s, 32, 64); s2 += __shfl_xor(s2, 32, 64);
    float mean = s * (1.f / 128.f);
    float rstd = rsqrtf(s2 * (1.f / 128.f) - mean * mean + 1e-5f);
#pragma unroll
    for (int gg = 0; gg < 4; gg++)
#pragma unroll
      for (int wq4 = 0; wq4 < 4; wq4++) {
        int c0 = gg * 32 + ((wq4 >> 1) << 4) + ((wq4 & 1) << 2) + (hh << 3);
        float4 gv = *(const float4*)(g + c0);
        float4 bv = *(const float4*)(be + c0);
        float v0 = (acc[gg][wq4 * 4 + 0] - mean) * rstd * gv.x + bv.x;
        float v1 = (acc[gg][wq4 * 4 + 1] - mean) * rstd * gv.y + bv.y;
        float v2 = (acc[gg][wq4 * 4 + 2] - mean) * rstd * gv.z + bv.z;
        float v3 = (acc[gg][wq4 * 4 + 3] - mean) * rstd * gv.w + bv.w;
        zpk[gg][wq4][0] = pkbf2(v0, v1);
        zpk[gg][wq4][1] = pkbf2(v2, v3);
      }
  }

  // ---- encoder layers ----
#pragma unroll 1
  for (int L = 0; L < 2; L++) {
    const u16* w1p = wse + (size_t)(L * 3 + 0) * 16384;
    const u16* w2p = wse + (size_t)(L * 3 + 1) * 16384;
    const u16* wrp = wse + (size_t)(L * 3 + 2) * 16384;
    unsigned hp2[4][4][2];
    // GEMM-A: h2 = relu(W1^T z + eb1), 8 k-groups, dbuf
    {
      f16v a2[4];
#pragma unroll
      for (int gg = 0; gg < 4; gg++) a2[gg] = zero16();
      bf8v wq[2][4];
#pragma unroll
      for (int gg = 0; gg < 4; gg++)
        wq[0][gg] = ld8(w1p + ((size_t)(hh * 128 + gg * 32 + r5)) * 8);
#pragma unroll
      for (int u = 0; u < 8; u++) {
        int cur = u & 1;
        if (u + 1 < 8) {
#pragma unroll
          for (int gg = 0; gg < 4; gg++)
            wq[cur ^ 1][gg] =
                ld8(w1p + ((size_t)((2 * (u + 1) + hh) * 128 + gg * 32 + r5)) * 8);
        }
        bf8v bfr = FRG(zpk, u);
#pragma unroll
        for (int gg = 0; gg < 4; gg++) a2[gg] = mfma32(wq[cur][gg], bfr, a2[gg]);
      }
#pragma unroll
      for (int gg = 0; gg < 4; gg++)
#pragma unroll
        for (int wq4 = 0; wq4 < 4; wq4++) {
          int c0 = gg * 32 + ((wq4 >> 1) << 4) + ((wq4 & 1) << 2) + (hh << 3);
          float4 bv = *(const float4*)(eb1 + L * 128 + c0);
          float v0 = fmaxf(a2[gg][wq4 * 4 + 0] + bv.x, 0.f);
          float v1 = fmaxf(a2[gg][wq4 * 4 + 1] + bv.y, 0.f);
          float v2 = fmaxf(a2[gg][wq4 * 4 + 2] + bv.z, 0.f);
          float v3 = fmaxf(a2[gg][wq4 * 4 + 3] + bv.w, 0.f);
          hp2[gg][wq4][0] = pkbf2(v0, v1);
          hp2[gg][wq4][1] = pkbf2(v2, v3);
        }
    }
    // GEMM-B: y = W2^T h2 + Wr^T z (16 virtual k-groups, dbuf)
#pragma unroll
    for (int gg = 0; gg < 4; gg++) acc[gg] = zero16();
    {
      bf8v wq[2][4];
#pragma unroll
      for (int gg = 0; gg < 4; gg++)
        wq[0][gg] = ld8(w2p + ((size_t)(hh * 128 + gg * 32 + r5)) * 8);
#pragma unroll
      for (int u = 0; u < 16; u++) {
        int cur = u & 1;
        if (u + 1 < 16) {
          int v = u + 1;
          const u16* wp = (v < 8) ? w2p : wrp;
          int kg = v & 7;
#pragma unroll
          for (int gg = 0; gg < 4; gg++)
            wq[cur ^ 1][gg] = ld8(wp + ((size_t)((2 * kg + hh) * 128 + gg * 32 + r5)) * 8);
        }
        bf8v bfr = (u < 8) ? FRG(hp2, u) : FRG(zpk, (u - 8));
#pragma unroll
        for (int gg = 0; gg < 4; gg++) acc[gg] = mfma32(wq[cur][gg], bfr, acc[gg]);
      }
    }
    float s = 0.f, s2 = 0.f;
#pragma unroll
    for (int gg = 0; gg < 4; gg++)
#pragma unroll
      for (int wq4 = 0; wq4 < 4; wq4++) {
        int c0 = gg * 32 + ((wq4 >> 1) << 4) + ((wq4 & 1) << 2) + (hh << 3);
        float4 bv2 = *(const float4*)(eb2 + L * 128 + c0);
        float4 bvr = *(const float4*)(ebr + L * 128 + c0);
        acc[gg][wq4 * 4 + 0] += bv2.x + bvr.x;
        acc[gg][wq4 * 4 + 1] += bv2.y + bvr.y;
        acc[gg][wq4 * 4 + 2] += bv2.z + bvr.z;
        acc[gg][wq4 * 4 + 3] += bv2.w + bvr.w;
#pragma unroll
        for (int sidx = 0; sidx < 4; sidx++) {
          float v = acc[gg][wq4 * 4 + sidx];
          s += v; s2 += v * v;
        }
      }
    s += __shfl_xor(s, 32, 64); s2 += __shfl_xor(s2, 32, 64);
    float mean = s * (1.f / 128.f);
    float rstd = rsqrtf(s2 * (1.f / 128.f) - mean * mean + 1e-5f);
#pragma unroll
    for (int gg = 0; gg < 4; gg++)
#pragma unroll
      for (int wq4 = 0; wq4 < 4; wq4++) {
        int c0 = gg * 32 + ((wq4 >> 1) << 4) + ((wq4 & 1) << 2) + (hh << 3);
        float4 gv = *(const float4*)(eg + L * 128 + c0);
        float4 bv = *(const float4*)(ebe + L * 128 + c0);
        float v0 = (acc[gg][wq4 * 4 + 0] - mean) * rstd * gv.x + bv.x;
        float v1 = (acc[gg][wq4 * 4 + 1] - mean) * rstd * gv.y + bv.y;
        float v2 = (acc[gg][wq4 * 4 + 2] - mean) * rstd * gv.z + bv.z;
        float v3 = (acc[gg][wq4 * 4 + 3] - mean) * rstd * gv.w + bv.w;
        unsigned plo = pkbf2(v0, v1), phi = pkbf2(v2, v3);
        if (L == 0) {
          zpk[gg][wq4][0] = plo;
          zpk[gg][wq4][1] = phi;
        } else {
          uint2 pv = {plo, phi};
          *(uint2*)(zst + (w * 32 + r5) * 132 + c0) = pv;  // de-permuted by address
        }
      }
  }

  // per-wave coalesced store of its own 32 rows (same-wave LDS RAW: no barrier)
#pragma unroll
  for (int it = 0; it < 8; it++) {
    int lu = it * 64 + lane;
    int rr = lu >> 4, seg = lu & 15;
    int orow = w * 32 + rr;
    *(uint4*)(zout + ((size_t)tile * 64 + orow) * 128 + seg * 8) =
        *(const uint4*)(zst + orow * 132 + seg * 8);
  }
}

// ---------------- K2: MultiHeadEMA (2-state scan) + residual + silu, IN-PLACE ----------------
__global__ __launch_bounds__(128) void k_ema(
    u16* __restrict__ z,
    const float* __restrict__ pdel, const float* __restrict__ palp,
    const float* __restrict__ pbet, const float* __restrict__ pgam,
    const float* __restrict__ pome) {
  __shared__ __align__(16) u16 zc[64 * 128];
  const int t = threadIdx.x;  // channel d
  const int bn = blockIdx.x;
  float p0 = 1.f / (1.f + __expf(-pdel[t * 2 + 0]));
  float p1 = 1.f / (1.f + __expf(-pdel[t * 2 + 1]));
  float q0 = 1.f - p0 / (1.f + __expf(-palp[t * 2 + 0]));
  float q1 = 1.f - p1 / (1.f + __expf(-palp[t * 2 + 1]));
  float w0 = p0 * pbet[t * 2 + 0] * pgam[t * 2 + 0] * EMA_SCALE;
  float w1 = p1 * pbet[t * 2 + 1] * pgam[t * 2 + 1] * EMA_SCALE;
  float om = pome[t];
  float s0 = 0.f, s1 = 0.f;
  u16* slab = z + (size_t)bn * KH;

  for (int ch = 0; ch < 4; ch++) {
    int nrow = (ch < 3) ? 64 : 63;
    int nval = nrow * 128;
    for (int i = t * 8; i < nval; i += 128 * 8)
      *(uint4*)(zc + i) = *(const uint4*)(slab + ch * 8192 + i);
    __syncthreads();
    for (int j0 = 0; j0 < nrow; j0 += 8) {
      float xs[8];
#pragma unroll
      for (int jj = 0; jj < 8; jj++)
        if (j0 + jj < nrow) xs[jj] = bf2f(zc[(j0 + jj) * 128 + t]);
#pragma unroll
      for (int jj = 0; jj < 8; jj++)
        if (j0 + jj < nrow) {
          float xv = xs[jj];
          s0 = q0 * s0 + xv;
          s1 = q1 * s1 + xv;
          float v = w0 * s0 + w1 * s1 + om * xv;
          xs[jj] = v / (1.f + __expf(-v));  // silu
        }
#pragma unroll
      for (int jj = 0; jj < 8; jj++)
        if (j0 + jj < nrow)
          zc[(j0 + jj) * 128 + t] = (u16)((__float_as_uint(xs[jj]) + 0x8000u) >> 16);
    }
    __syncthreads();
    for (int i = t * 8; i < nval; i += 128 * 8)
      *(uint4*)(slab + ch * 8192 + i) = *(const uint4*)(zc + i);
    __syncthreads();
  }
}

// ---------------- K3: head GEMM partials (K split into 30 chunks of 1088) ----------------
__global__ __launch_bounds__(256) void k_head(
    const u16* __restrict__ u, const u16* __restrict__ whs, float* __restrict__ part) {
  const int t = threadIdx.x;
  const int lane = t & 63, wid = t >> 6;
  const int quad = lane >> 4, lc = lane & 15;
  const int tile = blockIdx.x;  // 0..20
  const int ch = blockIdx.y;    // 0..29
  const int m0 = tile * 64 + wid * 16;
  const u16* Ab = u + (size_t)(m0 + lc) * KH + (size_t)ch * KPC;
  const int g0 = ch * (KPC / 8);  // base k-group
  f4v acc[6];
#pragma unroll
  for (int n = 0; n < 6; n++) acc[n] = (f4v){0.f, 0.f, 0.f, 0.f};
  bf8v a_nxt = ld8(Ab + quad * 8);
  bf8v b_nxt[6];
#pragma unroll
  for (int n = 0; n < 6; n++)
    b_nxt[n] = ld8(whs + ((size_t)(g0 + quad) * PRED + n * 16 + lc) * 8);
  for (int ks = 0; ks < HITER; ks++) {
    bf8v a_cur = a_nxt;
    bf8v b_cur[6];
#pragma unroll
    for (int n = 0; n < 6; n++) b_cur[n] = b_nxt[n];
    if (ks < HITER - 1) {
      a_nxt = ld8(Ab + (ks + 1) * 32 + quad * 8);
#pragma unroll
      for (int n = 0; n < 6; n++)
        b_nxt[n] = ld8(whs + ((size_t)(g0 + (ks + 1) * 4 + quad) * PRED + n * 16 + lc) * 8);
    }
#pragma unroll
    for (int n = 0; n < 6; n++) acc[n] = mfma16(a_cur, b_cur[n], acc[n]);
  }
#pragma unroll
  for (int n = 0; n < 6; n++) {
    int col = n * 16 + lc;
#pragma unroll
    for (int r = 0; r < 4; r++)
      part[((size_t)ch * BN + m0 + quad * 4 + r) * PRED + col] = acc[n][r];
  }
}

// ---------------- K4: reduce partials + bias -> fp32 out ----------------
__global__ __launch_bounds__(256) void k_red(
    const float* __restrict__ part, const float* __restrict__ hb, float* __restrict__ out) {
  int i = blockIdx.x * 256 + threadIdx.x;
  if (i >= BN * PRED) return;
  int row = i / PRED, col = i - row * PRED;
  float s = hb[col];
#pragma unroll 5
  for (int c = 0; c < CH; c++) s += part[((size_t)c * BN + row) * PRED + col];
  out[i] = s;
}

// ---------------- host ----------------
extern "C" void kernel_launch(void* const* d_in, const int* in_sizes, int n_in,
                              void* d_out, int out_size, void* d_ws, size_t ws_size,
                              hipStream_t stream) {
  const float* x      = (const float*)d_in[0];
  const float* fp_w1  = (const float*)d_in[1];
  const float* fp_b1  = (const float*)d_in[2];
  const float* fp_w2  = (const float*)d_in[3];
  const float* fp_b2  = (const float*)d_in[4];
  const float* fp_wr  = (const float*)d_in[5];
  const float* fp_br  = (const float*)d_in[6];
  const float* fp_g   = (const float*)d_in[7];
  const float* fp_be  = (const float*)d_in[8];
  const float* enc_w1 = (const float*)d_in[9];
  const float* enc_b1 = (const float*)d_in[10];
  const float* enc_w2 = (const float*)d_in[11];
  const float* enc_b2 = (const float*)d_in[12];
  const float* enc_wr = (const float*)d_in[13];
  const float* enc_br = (const float*)d_in[14];
  const float* enc_g  = (const float*)d_in[15];
  const float* enc_be = (const float*)d_in[16];
  const float* e_del  = (const float*)d_in[17];
  const float* e_alp  = (const float*)d_in[18];
  const float* e_bet  = (const float*)d_in[19];
  const float* e_gam  = (const float*)d_in[20];
  const float* e_om   = (const float*)d_in[21];
  const float* head_w = (const float*)d_in[22];
  const float* head_b = (const float*)d_in[23];

  // ws layout (bytes):
  //   [0, 87736320)             z3 / u  (bf16, [ROWS][128])
  //   [87736320, 103219200)     part    (fp32, [30][1344][96])
  //   [103219200, ...)          swizzled bf16 weights (~6.6 MB)
  char* base = (char*)d_ws;
  u16* z3 = (u16*)base;
  const size_t EZB = (size_t)ROWS * 128 * 2;        // 87,736,320
  float* part = (float*)(base + EZB);
  const size_t PARTB = (size_t)CH * BN * PRED * 4;  // 15,482,880
  u16* wb = (u16*)(base + EZB + PARTB);
  // wb offsets (u16): ws1=0(8192), ws2=8192(32768), wsr=40960(4096),
  //                   wse=45056(6*16384), wsh=143360(32640*96)
  u16* ws1 = wb;
  u16* ws2 = wb + 8192;
  u16* wsr = wb + 40960;
  u16* wse = wb + 45056;
  u16* wsh = wb + 143360;

  swz_all<<<560 + (KH * PRED + 255) / 256, 256, 0, stream>>>(
      fp_w1, fp_w2, fp_wr, enc_w1, enc_w2, enc_wr, head_w, wb, wsh);

  k_lem<<<ROWS / 64, 128, 0, stream>>>(x, ws1, fp_b1, ws2, wsr, fp_b2, fp_br, fp_g, fp_be,
                                       wse, enc_b1, enc_b2, enc_br, enc_g, enc_be, z3);
  k_ema<<<BN, 128, 0, stream>>>(z3, e_del, e_alp, e_bet, e_gam, e_om);
  k_head<<<dim3(21, CH), 256, 0, stream>>>(z3, wsh, part);
  k_red<<<(BN * PRED + 255) / 256, 256, 0, stream>>>(part, head_b, (float*)d_out);
}